// Round 5
// baseline (6980.933 us; speedup 1.0000x reference)
//
#include <hip/hip_runtime.h>
#include <hip/hip_bf16.h>
#include <math.h>

#define NBOX 4096
#define HDIM 128
#define G3   384   // 3*H

__device__ __forceinline__ float sigm(float x) { return 1.f / (1.f + expf(-x)); }
__device__ __forceinline__ float sigm_fast(float x) {
    return __builtin_amdgcn_rcpf(1.f + __expf(-x));
}
__device__ __forceinline__ float tanh_fast(float x) {
    x = fminf(15.f, fmaxf(-15.f, x));
    const float e2 = __expf(2.f * x);
    return (e2 - 1.f) * __builtin_amdgcn_rcpf(e2 + 1.f);
}
// DPP quad-perm broadcasts: quad lane k -> all 4 lanes of the quad
__device__ __forceinline__ float bcast_q0(float x) {
    return __int_as_float(__builtin_amdgcn_mov_dpp(__float_as_int(x), 0x00, 0xF, 0xF, false));
}
__device__ __forceinline__ float bcast_q1(float x) {
    return __int_as_float(__builtin_amdgcn_mov_dpp(__float_as_int(x), 0x55, 0xF, 0xF, false));
}

// C[M,N] = act(A[M,K] @ B[K,N] + bias[N]); row-major. BM=128,BN=64,BK=16.
__global__ __launch_bounds__(256) void gemm_f32(
    const float* __restrict__ A, const float* __restrict__ B,
    const float* __restrict__ bias, float* __restrict__ C,
    int M, int N, int K, int ldc, int act)
{
    __shared__ float As[16][132];
    __shared__ float Bs[16][68];
    const int tid = threadIdx.x;
    const int m0 = blockIdx.y * 128;
    const int n0 = blockIdx.x * 64;
    const int ak = tid & 15, am = tid >> 4;
    const int bn = tid & 63, bk = tid >> 6;
    const int tx = tid & 15, ty = tid >> 4;
    float acc[8][4] = {};
    for (int k0 = 0; k0 < K; k0 += 16) {
#pragma unroll
        for (int r = 0; r < 8; ++r)
            As[ak][am + 16 * r] = A[(size_t)(m0 + am + 16 * r) * K + k0 + ak];
#pragma unroll
        for (int r = 0; r < 4; ++r)
            Bs[bk + 4 * r][bn] = B[(size_t)(k0 + bk + 4 * r) * N + n0 + bn];
        __syncthreads();
#pragma unroll
        for (int k = 0; k < 16; ++k) {
            float4 a0 = *(const float4*)&As[k][ty * 8];
            float4 a1 = *(const float4*)&As[k][ty * 8 + 4];
            float4 b0 = *(const float4*)&Bs[k][tx * 4];
            float a[8] = {a0.x, a0.y, a0.z, a0.w, a1.x, a1.y, a1.z, a1.w};
            float b[4] = {b0.x, b0.y, b0.z, b0.w};
#pragma unroll
            for (int i = 0; i < 8; ++i)
#pragma unroll
                for (int j = 0; j < 4; ++j)
                    acc[i][j] = fmaf(a[i], b[j], acc[i][j]);
        }
        __syncthreads();
    }
#pragma unroll
    for (int i = 0; i < 8; ++i) {
        const int m = m0 + ty * 8 + i;
#pragma unroll
        for (int j = 0; j < 4; ++j) {
            const int n = n0 + tx * 4 + j;
            float v = acc[i][j] + bias[n];
            if (act) v = fmaxf(v, 0.f);
            C[(size_t)m * ldc + n] = v;
        }
    }
}

// Sequential GRU scan, one workgroup of 512 threads (8 waves, 2/SIMD).
// Quad layout: tid = i*4+g; g=0:r, g=1:z, g=2:n (g=3 duplicates n).
// Each thread holds its Whh column (128 f32 = 32 float4) in VGPRs.
// Round-3/4 profiles: VGPR_Count=84 — compiler SANK the weight loads into
// the loop (256 KB/step from L2 = 2048cyc bound). The opaque-asm pin below
// makes the loaded values non-rematerializable, forcing them to stay
// register-resident for the whole scan.
__global__ __launch_bounds__(512, 2) void gru_scan(
    const float* __restrict__ GI, const float* __restrict__ Whh,
    const float* __restrict__ bhh, const float* __restrict__ h0,
    double* __restrict__ esum_out, float* __restrict__ hfinal_out,
    float* __restrict__ D_out, int T)
{
    __shared__ float h_lds[2][HDIM];
    const int tid = threadIdx.x;
    const int i = tid >> 2;
    const int g = tid & 3;
    const int col = (g < 3 ? g : 2) * HDIM + i;   // PyTorch gate order r|z|n
    float4 w4[32];
#pragma unroll
    for (int q = 0; q < 32; ++q) {
        w4[q].x = Whh[(size_t)(4 * q + 0) * G3 + col];
        w4[q].y = Whh[(size_t)(4 * q + 1) * G3 + col];
        w4[q].z = Whh[(size_t)(4 * q + 2) * G3 + col];
        w4[q].w = Whh[(size_t)(4 * q + 3) * G3 + col];
    }
    // Pin: force all 128 weight floats into live VGPRs (not re-loadable).
#pragma unroll
    for (int q = 0; q < 32; ++q)
        asm volatile("" : "+v"(w4[q].x), "+v"(w4[q].y), "+v"(w4[q].z), "+v"(w4[q].w));
    const float bh = bhh[col];
    if (tid < HDIM) h_lds[0][tid] = h0 ? h0[tid] : 0.f;
    double esum = 0.0;
    float gi_cur = GI[col];
    __syncthreads();
    for (int t = 0; t < T; ++t) {
        const float gi_nxt = GI[(size_t)(t + 1) * G3 + col];  // padded row ok
        const float4* hb = (const float4*)h_lds[t & 1];
        float a0 = 0.f, a1 = 0.f, a2 = 0.f, a3 = 0.f;
#pragma unroll
        for (int q = 0; q < 32; ++q) {
            float4 h4 = hb[q];  // wave-uniform address: LDS broadcast
            a0 = fmaf(h4.x, w4[q].x, a0);
            a1 = fmaf(h4.y, w4[q].y, a1);
            a2 = fmaf(h4.z, w4[q].z, a2);
            a3 = fmaf(h4.w, w4[q].w, a3);
        }
        const float gh = (a0 + a1) + (a2 + a3) + bh;
        const float hp = h_lds[t & 1][i];
        const float s = sigm_fast(gi_cur + gh);
        const float r = bcast_q0(s);              // r gate from quad lane 0
        const float z = bcast_q1(s);              // z gate from quad lane 1
        const float n = tanh_fast(gi_cur + r * gh);
        const float hn = z * (hp - n) + n;        // (1-z)*n + z*hp
        if (g == 2) {
            h_lds[(t + 1) & 1][i] = hn;
            esum += (double)hn;
            if (D_out) D_out[(size_t)t * HDIM + i] = hn;
        }
        gi_cur = gi_nxt;
        __syncthreads();  // single barrier/step: dbuf covers both hazards
    }
    if (g == 2) {
        if (esum_out) esum_out[i] = esum;
        if (hfinal_out) hfinal_out[i] = h_lds[T & 1][i];
    }
}

// c2[j] = b_comb[j] + sum_k esum[k] * W_comb[128+k][j]
__global__ void prep_dec(const double* __restrict__ esum, const float* __restrict__ W_comb,
                         const float* __restrict__ b_comb, float* __restrict__ c2)
{
    __shared__ double es[HDIM];
    const int j = threadIdx.x;
    es[j] = esum[j];
    __syncthreads();
    double acc = (double)b_comb[j];
    for (int k = 0; k < HDIM; ++k)
        acc += es[k] * (double)W_comb[(HDIM + k) * HDIM + j];
    c2[j] = (float)acc;
}

__global__ __launch_bounds__(256) void out_row(
    const float* __restrict__ D, const float* __restrict__ Wout,
    const float* __restrict__ b_out, float* __restrict__ out)
{
    const int row = (blockIdx.x * 256 + threadIdx.x) >> 6;
    const int lane = threadIdx.x & 63;
    float v = D[(size_t)row * HDIM + lane] * Wout[lane]
            + D[(size_t)row * HDIM + 64 + lane] * Wout[64 + lane];
#pragma unroll
    for (int s = 32; s > 0; s >>= 1) v += __shfl_down(v, s);
    if (lane == 0) out[row] = sigm(v + b_out[0]);
}

__global__ void copy_lw(const float* __restrict__ lab, const float* __restrict__ wt,
                        float* __restrict__ out)
{
    const int i = blockIdx.x * 256 + threadIdx.x;
    if (i < NBOX) { out[NBOX + i] = lab[i]; out[2 * NBOX + i] = wt[i]; }
}

extern "C" void kernel_launch(void* const* d_in, const int* in_sizes, int n_in,
                              void* d_out, int out_size, void* d_ws, size_t ws_size,
                              hipStream_t stream)
{
    const float* boxes_feature = (const float*)d_in[0];
    const float* boxes_score   = (const float*)d_in[1];
    const float* boxes_box     = (const float*)d_in[2];
    const float* boxes_label   = (const float*)d_in[3];
    const float* boxes_weight  = (const float*)d_in[4];
    const float* W_appear = (const float*)d_in[6];
    const float* b_appear = (const float*)d_in[7];
    const float* W_s1     = (const float*)d_in[8];
    const float* b_s1     = (const float*)d_in[9];
    const float* W_s2     = (const float*)d_in[10];
    const float* b_s2     = (const float*)d_in[11];
    const float* W_box    = (const float*)d_in[12];
    const float* b_box    = (const float*)d_in[13];
    const float* W_all    = (const float*)d_in[14];
    const float* b_all    = (const float*)d_in[15];
    const float* enc_Wih  = (const float*)d_in[16];
    const float* enc_Whh  = (const float*)d_in[17];
    const float* enc_bih  = (const float*)d_in[18];
    const float* enc_bhh  = (const float*)d_in[19];
    const float* dec_Wih  = (const float*)d_in[20];
    const float* dec_Whh  = (const float*)d_in[21];
    const float* dec_bih  = (const float*)d_in[22];
    const float* dec_bhh  = (const float*)d_in[23];
    // d_in[24] W_attn, d_in[25] b_attn: no effect (softmax over singleton)
    const float* W_comb   = (const float*)d_in[26];
    const float* b_comb   = (const float*)d_in[27];
    const float* W_out    = (const float*)d_in[28];
    const float* b_out    = (const float*)d_in[29];

    float* out = (float*)d_out;
    float* ws = (float*)d_ws;
    size_t o = 0;
    float* T1   = ws + o; o += (size_t)NBOX * 512;      // score@W_s1+b (LINEAR)
    float* XCAT = ws + o; o += (size_t)NBOX * G3;
    float* X    = ws + o; o += (size_t)NBOX * HDIM;
    float* GIE  = ws + o; o += (size_t)(NBOX + 1) * G3;
    float* GID  = ws + o; o += (size_t)(NBOX + 1) * G3;
    float* DIN  = ws + o; o += (size_t)NBOX * HDIM;
    float* D    = ws + o; o += (size_t)NBOX * HDIM;
    o = (o + 1) & ~(size_t)1;
    double* esum = (double*)(ws + o); o += 256;
    float* henc = ws + o; o += 128;
    float* c2   = ws + o; o += 128;

    // ---- phase 1: parallel feature GEMMs ----
    gemm_f32<<<dim3(512 / 64, NBOX / 128), 256, 0, stream>>>(
        boxes_score, W_s1, b_s1, T1, NBOX, 512, 2560, 512, 0);
    gemm_f32<<<dim3(HDIM / 64, NBOX / 128), 256, 0, stream>>>(
        boxes_feature, W_appear, b_appear, XCAT + 0, NBOX, HDIM, 1024, G3, 1);
    gemm_f32<<<dim3(HDIM / 64, NBOX / 128), 256, 0, stream>>>(
        T1, W_s2, b_s2, XCAT + HDIM, NBOX, HDIM, 512, G3, 1);
    gemm_f32<<<dim3(HDIM / 64, NBOX / 128), 256, 0, stream>>>(
        boxes_box, W_box, b_box, XCAT + 2 * HDIM, NBOX, HDIM, 320, G3, 1);
    gemm_f32<<<dim3(HDIM / 64, NBOX / 128), 256, 0, stream>>>(
        XCAT, W_all, b_all, X, NBOX, HDIM, G3, HDIM, 1);

    // ---- encoder ----
    gemm_f32<<<dim3(G3 / 64, NBOX / 128), 256, 0, stream>>>(
        X, enc_Wih, enc_bih, GIE, NBOX, G3, HDIM, G3, 0);
    gru_scan<<<1, 512, 0, stream>>>(GIE, enc_Whh, enc_bhh, nullptr,
                                    esum, henc, nullptr, NBOX);

    // ---- decoder prep (applied = esum constant across steps) ----
    prep_dec<<<1, 128, 0, stream>>>(esum, W_comb, b_comb, c2);
    gemm_f32<<<dim3(HDIM / 64, NBOX / 128), 256, 0, stream>>>(
        X, W_comb, c2, DIN, NBOX, HDIM, HDIM, HDIM, 1);
    gemm_f32<<<dim3(G3 / 64, NBOX / 128), 256, 0, stream>>>(
        DIN, dec_Wih, dec_bih, GID, NBOX, G3, HDIM, G3, 0);

    // ---- decoder scan ----
    gru_scan<<<1, 512, 0, stream>>>(GID, dec_Whh, dec_bhh, henc,
                                    nullptr, nullptr, D, NBOX);

    // ---- epilogue ----
    out_row<<<NBOX / 4, 256, 0, stream>>>(D, W_out, b_out, out);
    copy_lw<<<NBOX / 256, 256, 0, stream>>>(boxes_label, boxes_weight, out);
}

// Round 6
// 5135.611 us; speedup vs baseline: 1.3593x; 1.3593x over previous
//
#include <hip/hip_runtime.h>
#include <hip/hip_bf16.h>
#include <math.h>

#define NBOX 4096
#define HDIM 128
#define G3   384   // 3*H

typedef _Float16 half2v __attribute__((ext_vector_type(2)));

__device__ __forceinline__ float sigm(float x) { return 1.f / (1.f + expf(-x)); }
__device__ __forceinline__ float sigm_fast(float x) {
    return __builtin_amdgcn_rcpf(1.f + __expf(-x));
}
__device__ __forceinline__ float tanh_fast(float x) {
    x = fminf(15.f, fmaxf(-15.f, x));
    const float e2 = __expf(2.f * x);
    return (e2 - 1.f) * __builtin_amdgcn_rcpf(e2 + 1.f);
}
// DPP quad-perm broadcasts: quad lane k -> all 4 lanes of the quad
__device__ __forceinline__ float bcast_q0(float x) {
    return __int_as_float(__builtin_amdgcn_mov_dpp(__float_as_int(x), 0x00, 0xF, 0xF, false));
}
__device__ __forceinline__ float bcast_q1(float x) {
    return __int_as_float(__builtin_amdgcn_mov_dpp(__float_as_int(x), 0x55, 0xF, 0xF, false));
}
// v_dot2_f32_f16: exact f16 products, f32 accumulate
__device__ __forceinline__ float fdot2(unsigned int h2, unsigned int w2, float acc) {
    return __builtin_amdgcn_fdot2(__builtin_bit_cast(half2v, h2),
                                  __builtin_bit_cast(half2v, w2), acc, false);
}

// C[M,N] = act(A[M,K] @ B[K,N] + bias[N]); row-major. BM=128,BN=64,BK=16.
__global__ __launch_bounds__(256) void gemm_f32(
    const float* __restrict__ A, const float* __restrict__ B,
    const float* __restrict__ bias, float* __restrict__ C,
    int M, int N, int K, int ldc, int act)
{
    __shared__ float As[16][132];
    __shared__ float Bs[16][68];
    const int tid = threadIdx.x;
    const int m0 = blockIdx.y * 128;
    const int n0 = blockIdx.x * 64;
    const int ak = tid & 15, am = tid >> 4;
    const int bn = tid & 63, bk = tid >> 6;
    const int tx = tid & 15, ty = tid >> 4;
    float acc[8][4] = {};
    for (int k0 = 0; k0 < K; k0 += 16) {
#pragma unroll
        for (int r = 0; r < 8; ++r)
            As[ak][am + 16 * r] = A[(size_t)(m0 + am + 16 * r) * K + k0 + ak];
#pragma unroll
        for (int r = 0; r < 4; ++r)
            Bs[bk + 4 * r][bn] = B[(size_t)(k0 + bk + 4 * r) * N + n0 + bn];
        __syncthreads();
#pragma unroll
        for (int k = 0; k < 16; ++k) {
            float4 a0 = *(const float4*)&As[k][ty * 8];
            float4 a1 = *(const float4*)&As[k][ty * 8 + 4];
            float4 b0 = *(const float4*)&Bs[k][tx * 4];
            float a[8] = {a0.x, a0.y, a0.z, a0.w, a1.x, a1.y, a1.z, a1.w};
            float b[4] = {b0.x, b0.y, b0.z, b0.w};
#pragma unroll
            for (int i = 0; i < 8; ++i)
#pragma unroll
                for (int j = 0; j < 4; ++j)
                    acc[i][j] = fmaf(a[i], b[j], acc[i][j]);
        }
        __syncthreads();
    }
#pragma unroll
    for (int i = 0; i < 8; ++i) {
        const int m = m0 + ty * 8 + i;
#pragma unroll
        for (int j = 0; j < 4; ++j) {
            const int n = n0 + tx * 4 + j;
            float v = acc[i][j] + bias[n];
            if (act) v = fmaxf(v, 0.f);
            C[(size_t)m * ldc + n] = v;
        }
    }
}

// Sequential GRU scan, one workgroup of 512 threads (8 waves, 2/SIMD).
// Quad layout: tid = i*4+g; g=0:r, g=1:z, g=2:n (g=3 dup).
// Rounds 3-5: allocator refuses 128 live f32 weights/thread (VGPR=84,
// re-fetch 256KB/step from L2/scratch = 2048cyc bound). Fix: f16 weights
// packed 2/reg -> 64 VGPRs/thread, matvec via v_dot2_f32_f16 (exact f16
// products, f32 accumulate). h state in LDS as f16; gi stays f32.
// Whh~N(0,4e-4), |h|<1: f16 rel err 5e-4 -> output shift <=1 bf16 bucket.
__global__ __launch_bounds__(512, 2) void gru_scan(
    const float* __restrict__ GI, const float* __restrict__ Whh,
    const float* __restrict__ bhh, const float* __restrict__ h0,
    double* __restrict__ esum_out, float* __restrict__ hfinal_out,
    float* __restrict__ D_out, int T)
{
    __shared__ unsigned short h16[2][HDIM];   // f16 state, double-buffered
    const int tid = threadIdx.x;
    const int i = tid >> 2;
    const int g = tid & 3;
    const int col = (g < 3 ? g : 2) * HDIM + i;   // PyTorch gate order r|z|n
    unsigned int w2[64];                           // 128 f16 weights, packed
#pragma unroll
    for (int p = 0; p < 64; ++p) {
        const _Float16 lo = (_Float16)Whh[(size_t)(2 * p)     * G3 + col];
        const _Float16 hi = (_Float16)Whh[(size_t)(2 * p + 1) * G3 + col];
        w2[p] = (unsigned int)__builtin_bit_cast(unsigned short, lo)
              | ((unsigned int)__builtin_bit_cast(unsigned short, hi) << 16);
    }
#pragma unroll
    for (int p = 0; p < 64; ++p) asm volatile("" : "+v"(w2[p]));  // pin live
    const float bh = bhh[col];
    if (tid < HDIM)
        h16[0][tid] = __builtin_bit_cast(unsigned short,
                                         (_Float16)(h0 ? h0[tid] : 0.f));
    double esum = 0.0;
    float gi_cur = GI[col];
    __syncthreads();
    for (int t = 0; t < T; ++t) {
        const float gi_nxt = GI[(size_t)(t + 1) * G3 + col];  // padded row ok
        const uint4* hb = (const uint4*)h16[t & 1];
        float a0 = 0.f, a1 = 0.f, a2 = 0.f, a3 = 0.f;
#pragma unroll
        for (int q = 0; q < 16; ++q) {
            const uint4 u = hb[q];   // wave-uniform addr: LDS broadcast, 8 f16
            a0 = fdot2(u.x, w2[4 * q + 0], a0);
            a1 = fdot2(u.y, w2[4 * q + 1], a1);
            a2 = fdot2(u.z, w2[4 * q + 2], a2);
            a3 = fdot2(u.w, w2[4 * q + 3], a3);
        }
        const float gh = (a0 + a1) + (a2 + a3) + bh;
        const float hp = (float)__builtin_bit_cast(_Float16, h16[t & 1][i]);
        const float s = sigm_fast(gi_cur + gh);
        const float r = bcast_q0(s);              // r gate from quad lane 0
        const float z = bcast_q1(s);              // z gate from quad lane 1
        const float n = tanh_fast(gi_cur + r * gh);
        const float hn = z * (hp - n) + n;        // (1-z)*n + z*hp
        if (g == 2) {
            h16[(t + 1) & 1][i] = __builtin_bit_cast(unsigned short, (_Float16)hn);
            esum += (double)hn;
            if (D_out) D_out[(size_t)t * HDIM + i] = hn;
        }
        gi_cur = gi_nxt;
        __syncthreads();  // single barrier/step: dbuf covers both hazards
    }
    if (g == 2) {
        if (esum_out) esum_out[i] = esum;
        if (hfinal_out)
            hfinal_out[i] = (float)__builtin_bit_cast(_Float16, h16[T & 1][i]);
    }
}

// c2[j] = b_comb[j] + sum_k esum[k] * W_comb[128+k][j]
__global__ void prep_dec(const double* __restrict__ esum, const float* __restrict__ W_comb,
                         const float* __restrict__ b_comb, float* __restrict__ c2)
{
    __shared__ double es[HDIM];
    const int j = threadIdx.x;
    es[j] = esum[j];
    __syncthreads();
    double acc = (double)b_comb[j];
    for (int k = 0; k < HDIM; ++k)
        acc += es[k] * (double)W_comb[(HDIM + k) * HDIM + j];
    c2[j] = (float)acc;
}

__global__ __launch_bounds__(256) void out_row(
    const float* __restrict__ D, const float* __restrict__ Wout,
    const float* __restrict__ b_out, float* __restrict__ out)
{
    const int row = (blockIdx.x * 256 + threadIdx.x) >> 6;
    const int lane = threadIdx.x & 63;
    float v = D[(size_t)row * HDIM + lane] * Wout[lane]
            + D[(size_t)row * HDIM + 64 + lane] * Wout[64 + lane];
#pragma unroll
    for (int s = 32; s > 0; s >>= 1) v += __shfl_down(v, s);
    if (lane == 0) out[row] = sigm(v + b_out[0]);
}

__global__ void copy_lw(const float* __restrict__ lab, const float* __restrict__ wt,
                        float* __restrict__ out)
{
    const int i = blockIdx.x * 256 + threadIdx.x;
    if (i < NBOX) { out[NBOX + i] = lab[i]; out[2 * NBOX + i] = wt[i]; }
}

extern "C" void kernel_launch(void* const* d_in, const int* in_sizes, int n_in,
                              void* d_out, int out_size, void* d_ws, size_t ws_size,
                              hipStream_t stream)
{
    const float* boxes_feature = (const float*)d_in[0];
    const float* boxes_score   = (const float*)d_in[1];
    const float* boxes_box     = (const float*)d_in[2];
    const float* boxes_label   = (const float*)d_in[3];
    const float* boxes_weight  = (const float*)d_in[4];
    const float* W_appear = (const float*)d_in[6];
    const float* b_appear = (const float*)d_in[7];
    const float* W_s1     = (const float*)d_in[8];
    const float* b_s1     = (const float*)d_in[9];
    const float* W_s2     = (const float*)d_in[10];
    const float* b_s2     = (const float*)d_in[11];
    const float* W_box    = (const float*)d_in[12];
    const float* b_box    = (const float*)d_in[13];
    const float* W_all    = (const float*)d_in[14];
    const float* b_all    = (const float*)d_in[15];
    const float* enc_Wih  = (const float*)d_in[16];
    const float* enc_Whh  = (const float*)d_in[17];
    const float* enc_bih  = (const float*)d_in[18];
    const float* enc_bhh  = (const float*)d_in[19];
    const float* dec_Wih  = (const float*)d_in[20];
    const float* dec_Whh  = (const float*)d_in[21];
    const float* dec_bih  = (const float*)d_in[22];
    const float* dec_bhh  = (const float*)d_in[23];
    // d_in[24] W_attn, d_in[25] b_attn: no effect (softmax over singleton)
    const float* W_comb   = (const float*)d_in[26];
    const float* b_comb   = (const float*)d_in[27];
    const float* W_out    = (const float*)d_in[28];
    const float* b_out    = (const float*)d_in[29];

    float* out = (float*)d_out;
    float* ws = (float*)d_ws;
    size_t o = 0;
    float* T1   = ws + o; o += (size_t)NBOX * 512;      // score@W_s1+b (LINEAR)
    float* XCAT = ws + o; o += (size_t)NBOX * G3;
    float* X    = ws + o; o += (size_t)NBOX * HDIM;
    float* GIE  = ws + o; o += (size_t)(NBOX + 1) * G3;
    float* GID  = ws + o; o += (size_t)(NBOX + 1) * G3;
    float* DIN  = ws + o; o += (size_t)NBOX * HDIM;
    float* D    = ws + o; o += (size_t)NBOX * HDIM;
    o = (o + 1) & ~(size_t)1;
    double* esum = (double*)(ws + o); o += 256;
    float* henc = ws + o; o += 128;
    float* c2   = ws + o; o += 128;

    // ---- phase 1: parallel feature GEMMs ----
    gemm_f32<<<dim3(512 / 64, NBOX / 128), 256, 0, stream>>>(
        boxes_score, W_s1, b_s1, T1, NBOX, 512, 2560, 512, 0);
    gemm_f32<<<dim3(HDIM / 64, NBOX / 128), 256, 0, stream>>>(
        boxes_feature, W_appear, b_appear, XCAT + 0, NBOX, HDIM, 1024, G3, 1);
    gemm_f32<<<dim3(HDIM / 64, NBOX / 128), 256, 0, stream>>>(
        T1, W_s2, b_s2, XCAT + HDIM, NBOX, HDIM, 512, G3, 1);
    gemm_f32<<<dim3(HDIM / 64, NBOX / 128), 256, 0, stream>>>(
        boxes_box, W_box, b_box, XCAT + 2 * HDIM, NBOX, HDIM, 320, G3, 1);
    gemm_f32<<<dim3(HDIM / 64, NBOX / 128), 256, 0, stream>>>(
        XCAT, W_all, b_all, X, NBOX, HDIM, G3, HDIM, 1);

    // ---- encoder ----
    gemm_f32<<<dim3(G3 / 64, NBOX / 128), 256, 0, stream>>>(
        X, enc_Wih, enc_bih, GIE, NBOX, G3, HDIM, G3, 0);
    gru_scan<<<1, 512, 0, stream>>>(GIE, enc_Whh, enc_bhh, nullptr,
                                    esum, henc, nullptr, NBOX);

    // ---- decoder prep (applied = esum constant across steps) ----
    prep_dec<<<1, 128, 0, stream>>>(esum, W_comb, b_comb, c2);
    gemm_f32<<<dim3(HDIM / 64, NBOX / 128), 256, 0, stream>>>(
        X, W_comb, c2, DIN, NBOX, HDIM, HDIM, HDIM, 1);
    gemm_f32<<<dim3(G3 / 64, NBOX / 128), 256, 0, stream>>>(
        DIN, dec_Wih, dec_bih, GID, NBOX, G3, HDIM, G3, 0);

    // ---- decoder scan ----
    gru_scan<<<1, 512, 0, stream>>>(GID, dec_Whh, dec_bhh, henc,
                                    nullptr, nullptr, D, NBOX);

    // ---- epilogue ----
    out_row<<<NBOX / 4, 256, 0, stream>>>(D, W_out, b_out, out);
    copy_lw<<<NBOX / 256, 256, 0, stream>>>(boxes_label, boxes_weight, out);
}